// Round 11
// baseline (197.867 us; speedup 1.0000x reference)
//
#include <hip/hip_runtime.h>

#define N_NODESC 100000
#define N_EDGESC 1600000
#define BN_EPSC 1e-5f
#define NBUCK 1024              // coarse buckets (dst>>7, 128 nodes each), 782 used
#define NUSED 782               // ceil(100000/128)
#define SBLK 256                // castsort blocks
#define EPB (N_EDGESC / SBLK)   // 6250 edges per block
#define MT 128                  // nodes per MLP block
#define BCAPG 2304              // global per-bucket stride (mean 1562, ~18 sigma)
#define NSPREAD 16              // BN-stat atomic spreading (Guideline 12)

// ---------------------------------------------------------------------------
// K_castsort: ONE preprocessing kernel.  (R2 verbatim — proven)
// packed = src(17b) | attr<<17(2b) | (dst&127)<<19(7b).
// ---------------------------------------------------------------------------
__global__ __launch_bounds__(1024) void k_castsort(
    const int* __restrict__ ei, const int* __restrict__ ea,
    const float* __restrict__ x, uint2* __restrict__ xh4,
    int* __restrict__ gcur, int* __restrict__ tmp)
{
    __shared__ int ledge[EPB + 22];     // 6272 sorted packed edges
    __shared__ int cnt[NBUCK];
    __shared__ int cstart[NBUCK + 1];
    __shared__ int cur[NBUCK];
    __shared__ int gofs[NBUCK];
    __shared__ int wtot[16];
    const int t = threadIdx.x;
    const int k = blockIdx.x;

    cnt[t] = 0;
    {   // ---- bf16 cast, batched ----
        const float4* x4 = (const float4*)x;
        const int g = k * 1024 + t;
        float4 v[7];
        bool m[7];
        #pragma unroll
        for (int i = 0; i < 7; i++) {
            const int idx = g + i * (SBLK * 1024);
            m[i] = (idx < N_NODESC * 16);
            if (m[i]) v[i] = x4[idx];
        }
        #pragma unroll
        for (int i = 0; i < 7; i++) {
            if (m[i]) {
                const int idx = g + i * (SBLK * 1024);
                unsigned int a = __float_as_uint(v[i].x);
                unsigned int b = __float_as_uint(v[i].y);
                unsigned int c = __float_as_uint(v[i].z);
                unsigned int d = __float_as_uint(v[i].w);
                a = (a + 0x7FFFu + ((a >> 16) & 1u)) >> 16;
                b = (b + 0x7FFFu + ((b >> 16) & 1u)) >> 16;
                c = (c + 0x7FFFu + ((c >> 16) & 1u)) >> 16;
                d = (d + 0x7FFFu + ((d >> 16) & 1u)) >> 16;
                xh4[idx] = make_uint2(a | (b << 16), c | (d << 16));
            }
        }
    }
    __syncthreads();        // cnt zeroed before counting

    int pk[7], bk[7];
    const int base = k * EPB;
    #pragma unroll
    for (int i = 0; i < 7; i++) {
        const int e = base + i * 1024 + t;
        if (e < base + EPB) {
            const int src = ei[e];
            const int dst = ei[N_EDGESC + e];
            const int a = ea[e];
            pk[i] = src | (a << 17) | ((dst & 127) << 19);
            bk[i] = dst >> 7;
            atomicAdd(&cnt[bk[i]], 1);
        } else bk[i] = -1;
    }
    __syncthreads();

    {   // exclusive scan of 1024 counts
        const int lane = t & 63;
        const int w = t >> 6;
        const int v = cnt[t];
        int inc = v;
        #pragma unroll
        for (int d = 1; d < 64; d <<= 1) {
            const int u = __shfl_up(inc, d);
            if (lane >= d) inc += u;
        }
        if (lane == 63) wtot[w] = inc;
        __syncthreads();
        int add = 0;
        #pragma unroll
        for (int w2 = 0; w2 < 16; w2++) if (w2 < w) add += wtot[w2];
        const int ex = inc - v + add;
        cstart[t] = ex;
        cur[t] = ex;
        if (t == 1023) cstart[NBUCK] = ex + v;
    }
    __syncthreads();

    #pragma unroll
    for (int i = 0; i < 7; i++) {
        if (bk[i] >= 0) {
            const int pos = atomicAdd(&cur[bk[i]], 1);
            ledge[pos] = pk[i];
        }
    }
    {
        const int c = cnt[t];
        if (c > 0) gofs[t] = atomicAdd(&gcur[t], c);
    }
    __syncthreads();

    for (int i = t; i < EPB; i += 1024) {
        int lo = 0, hi = NBUCK;
        #pragma unroll
        for (int s = 0; s < 10; s++) {
            const int mid = (lo + hi) >> 1;
            if (cstart[mid] <= i) lo = mid; else hi = mid;
        }
        const int o = gofs[lo] + (i - cstart[lo]);
        if (o < BCAPG) tmp[lo * BCAPG + o] = ledge[i];
    }
}

// ---------------------------------------------------------------------------
// K_aggmlp1 (R10: LDS union -> 3 blocks/CU single-round residency):
//  R10 diagnosis: 63.5KB LDS -> 2 blocks/CU -> 782 blocks run in TWO
//  dispatch rounds (512 + 270, second round half-idle).  43.4us gather
//  floor x 3.05/2 parallelism loss = 66us ~ observed 64.5.  Fix: packedL
//  (phase A) / lW (phase B) / redS,redQ (phase C) are never simultaneously
//  live -> one 16KB union; W1 staged AFTER phase A (L2-hot after round 1,
//  ~0.5us).  LDS 63488 -> 54272 -> 3 blocks/CU, all blocks co-resident.
//  Dynamic node scheduling (R10) was null -> reverted to static (R8).
// ---------------------------------------------------------------------------
__global__ __launch_bounds__(512) void k_aggmlp1(
    const ushort* __restrict__ xh, const float* __restrict__ emb,
    const float* __restrict__ x, const float* __restrict__ epsp,
    const int* __restrict__ gcur, const int* __restrict__ tmp,
    const float* __restrict__ W1, const float* __restrict__ b1,
    float* __restrict__ out, float* __restrict__ cs, float* __restrict__ css)
{
    __shared__ float uni[4096];         // 16384B union: packedL | lW | redS/redQ
    __shared__ float lin[MT][68];       // 34816B
    __shared__ int cnt[128];
    __shared__ int cst[128];
    __shared__ int cur[128];
    __shared__ float emL[4][68];        // padded: rows 68 words apart
    const int t = threadIdx.x;
    const int b = blockIdx.x;
    const int start = b * BCAPG;
    int* packedL = (int*)uni;           // phase A: sorted edges (9216B used)

    int cntb = gcur[b];
    if (cntb > BCAPG) cntb = BCAPG;
    if (t < 128) cnt[t] = 0;
    if (t < 256) emL[t >> 6][t & 63] = emb[t];
    __syncthreads();

    // pass 1: per-node counts
    for (int e = t; e < cntb; e += 512)
        atomicAdd(&cnt[(tmp[start + e] >> 19) & 127], 1);
    __syncthreads();
    if (t < 64) {   // scan 128 counts (two 64-lane halves)
        const int lane = t;
        const int v0 = cnt[lane];
        const int v1 = cnt[64 + lane];
        int i0 = v0, i1 = v1;
        #pragma unroll
        for (int d = 1; d < 64; d <<= 1) {
            const int u0 = __shfl_up(i0, d);
            const int u1 = __shfl_up(i1, d);
            if (lane >= d) { i0 += u0; i1 += u1; }
        }
        const int tot0 = __shfl(i0, 63);
        cst[lane] = i0 - v0;
        cst[64 + lane] = tot0 + i1 - v1;
        cur[lane] = i0 - v0;
        cur[64 + lane] = tot0 + i1 - v1;
    }
    __syncthreads();
    // pass 2: place node-sorted into LDS
    for (int e = t; e < cntb; e += 512) {
        const int p = tmp[start + e];
        const int pos = atomicAdd(&cur[(p >> 19) & 127], 1);
        if (pos < BCAPG) packedL[pos] = p;
    }
    __syncthreads();

    // ---- phase A: aggregate; group g -> nodes g*2,g*2+1; lane q = octet -
    {
        const int g = t >> 3;
        const int q = t & 7;                 // floats [q*8, q*8+8)
        const float sc1 = 1.0f + epsp[0];
        const uint4* xv8 = (const uint4*)xh; // 16B = 8 bf16 per lane
        const float4* x4 = (const float4*)x;
        const float* eq = &emL[0][0] + q * 8;
        for (int j = 0; j < 2; j++) {
            const int nl = g * 2 + j;
            const int n = b * 128 + nl;
            int e = cst[nl];
            const int ee = cur[nl];           // cur == end after pass 2
            float4 aL = make_float4(0.f, 0.f, 0.f, 0.f);
            float4 aH = make_float4(0.f, 0.f, 0.f, 0.f);
            if (n < N_NODESC) {
                const float4 v0 = x4[(size_t)n * 16 + q * 2];
                const float4 v1 = x4[(size_t)n * 16 + q * 2 + 1];
                aL.x = sc1 * v0.x; aL.y = sc1 * v0.y;
                aL.z = sc1 * v0.z; aL.w = sc1 * v0.w;
                aH.x = sc1 * v1.x; aH.y = sc1 * v1.y;
                aH.z = sc1 * v1.z; aH.w = sc1 * v1.w;
            }
            for (; e + 2 <= ee; e += 2) {
                const int p0 = packedL[e];
                const int p1 = packedL[e + 1];
                const uint4 u0 = xv8[(size_t)(p0 & 0x1FFFF) * 8 + q];
                const uint4 u1 = xv8[(size_t)(p1 & 0x1FFFF) * 8 + q];
                const float* e0 = eq + ((p0 >> 17) & 3) * 68;
                const float* e1 = eq + ((p1 >> 17) & 3) * 68;
                const float4 t0L = *(const float4*)(e0);
                const float4 t0H = *(const float4*)(e0 + 4);
                const float4 t1L = *(const float4*)(e1);
                const float4 t1H = *(const float4*)(e1 + 4);
                aL.x += fmaxf(__uint_as_float(u0.x << 16)          + t0L.x, 0.f)
                      + fmaxf(__uint_as_float(u1.x << 16)          + t1L.x, 0.f);
                aL.y += fmaxf(__uint_as_float(u0.x & 0xFFFF0000u)  + t0L.y, 0.f)
                      + fmaxf(__uint_as_float(u1.x & 0xFFFF0000u)  + t1L.y, 0.f);
                aL.z += fmaxf(__uint_as_float(u0.y << 16)          + t0L.z, 0.f)
                      + fmaxf(__uint_as_float(u1.y << 16)          + t1L.z, 0.f);
                aL.w += fmaxf(__uint_as_float(u0.y & 0xFFFF0000u)  + t0L.w, 0.f)
                      + fmaxf(__uint_as_float(u1.y & 0xFFFF0000u)  + t1L.w, 0.f);
                aH.x += fmaxf(__uint_as_float(u0.z << 16)          + t0H.x, 0.f)
                      + fmaxf(__uint_as_float(u1.z << 16)          + t1H.x, 0.f);
                aH.y += fmaxf(__uint_as_float(u0.z & 0xFFFF0000u)  + t0H.y, 0.f)
                      + fmaxf(__uint_as_float(u1.z & 0xFFFF0000u)  + t1H.y, 0.f);
                aH.z += fmaxf(__uint_as_float(u0.w << 16)          + t0H.z, 0.f)
                      + fmaxf(__uint_as_float(u1.w << 16)          + t1H.z, 0.f);
                aH.w += fmaxf(__uint_as_float(u0.w & 0xFFFF0000u)  + t0H.w, 0.f)
                      + fmaxf(__uint_as_float(u1.w & 0xFFFF0000u)  + t1H.w, 0.f);
            }
            for (; e < ee; e++) {
                const int p0 = packedL[e];
                const uint4 u0 = xv8[(size_t)(p0 & 0x1FFFF) * 8 + q];
                const float* e0 = eq + ((p0 >> 17) & 3) * 68;
                const float4 t0L = *(const float4*)(e0);
                const float4 t0H = *(const float4*)(e0 + 4);
                aL.x += fmaxf(__uint_as_float(u0.x << 16)         + t0L.x, 0.f);
                aL.y += fmaxf(__uint_as_float(u0.x & 0xFFFF0000u) + t0L.y, 0.f);
                aL.z += fmaxf(__uint_as_float(u0.y << 16)         + t0L.z, 0.f);
                aL.w += fmaxf(__uint_as_float(u0.y & 0xFFFF0000u) + t0L.w, 0.f);
                aH.x += fmaxf(__uint_as_float(u0.z << 16)         + t0H.x, 0.f);
                aH.y += fmaxf(__uint_as_float(u0.z & 0xFFFF0000u) + t0H.y, 0.f);
                aH.z += fmaxf(__uint_as_float(u0.w << 16)         + t0H.z, 0.f);
                aH.w += fmaxf(__uint_as_float(u0.w & 0xFFFF0000u) + t0H.w, 0.f);
            }
            // h_pre -> LDS tile (own cells only; no cross-thread hazard)
            *(float4*)&lin[nl][q * 8]     = aL;
            *(float4*)&lin[nl][q * 8 + 4] = aH;
        }
    }
    __syncthreads();    // phase A done: packedL dead, lin complete

    {   // ---- stage W1 into the union (L2-hot after round 1; ~0.5us) -----
        const float4* W4 = (const float4*)W1;
        float4* lw4 = (float4*)uni;
        lw4[t] = W4[t];
        lw4[512 + t] = W4[512 + t];
    }
    __syncthreads();    // lW ready

    // ---- phase B: h1 = lin @ W1 + b1 ; store; BN sums -------------------
    const int gc = t & 7;          // col group: cols [gc*8, gc*8+8)
    const int r0 = t >> 3;         // rows r0, r0+64
    const float4* lW4 = (const float4*)uni;
    const float4* b4 = (const float4*)b1;
    const float4 bb0 = b4[gc * 2 + 0];
    const float4 bb1 = b4[gc * 2 + 1];
    float4 a00 = bb0, a01 = bb1;   // row r0
    float4 a10 = bb0, a11 = bb1;   // row r0+64
    for (int k = 0; k < 64; k += 2) {
        const float v0a = lin[r0][k];
        const float v0b = lin[r0][k + 1];
        const float v1a = lin[r0 + 64][k];
        const float v1b = lin[r0 + 64][k + 1];
        const float4 w0a = lW4[k * 16 + gc * 2 + 0];
        const float4 w1a = lW4[k * 16 + gc * 2 + 1];
        const float4 w0b = lW4[(k + 1) * 16 + gc * 2 + 0];
        const float4 w1b = lW4[(k + 1) * 16 + gc * 2 + 1];
        a00.x = fmaf(v0a, w0a.x, a00.x); a00.y = fmaf(v0a, w0a.y, a00.y);
        a00.z = fmaf(v0a, w0a.z, a00.z); a00.w = fmaf(v0a, w0a.w, a00.w);
        a01.x = fmaf(v0a, w1a.x, a01.x); a01.y = fmaf(v0a, w1a.y, a01.y);
        a01.z = fmaf(v0a, w1a.z, a01.z); a01.w = fmaf(v0a, w1a.w, a01.w);
        a10.x = fmaf(v1a, w0a.x, a10.x); a10.y = fmaf(v1a, w0a.y, a10.y);
        a10.z = fmaf(v1a, w0a.z, a10.z); a10.w = fmaf(v1a, w0a.w, a10.w);
        a11.x = fmaf(v1a, w1a.x, a11.x); a11.y = fmaf(v1a, w1a.y, a11.y);
        a11.z = fmaf(v1a, w1a.z, a11.z); a11.w = fmaf(v1a, w1a.w, a11.w);
        a00.x = fmaf(v0b, w0b.x, a00.x); a00.y = fmaf(v0b, w0b.y, a00.y);
        a00.z = fmaf(v0b, w0b.z, a00.z); a00.w = fmaf(v0b, w0b.w, a00.w);
        a01.x = fmaf(v0b, w1b.x, a01.x); a01.y = fmaf(v0b, w1b.y, a01.y);
        a01.z = fmaf(v0b, w1b.z, a01.z); a01.w = fmaf(v0b, w1b.w, a01.w);
        a10.x = fmaf(v1b, w0b.x, a10.x); a10.y = fmaf(v1b, w0b.y, a10.y);
        a10.z = fmaf(v1b, w0b.z, a10.z); a10.w = fmaf(v1b, w0b.w, a10.w);
        a11.x = fmaf(v1b, w1b.x, a11.x); a11.y = fmaf(v1b, w1b.y, a11.y);
        a11.z = fmaf(v1b, w1b.z, a11.z); a11.w = fmaf(v1b, w1b.w, a11.w);
    }
    const int n0 = b * MT + r0;
    const int n1 = n0 + 64;
    const float msk0 = (n0 < N_NODESC) ? 1.0f : 0.0f;
    const float msk1 = (n1 < N_NODESC) ? 1.0f : 0.0f;
    float4* o4 = (float4*)out;
    if (n0 < N_NODESC) {
        o4[(size_t)n0 * 16 + gc * 2 + 0] = a00;
        o4[(size_t)n0 * 16 + gc * 2 + 1] = a01;
    }
    if (n1 < N_NODESC) {
        o4[(size_t)n1 * 16 + gc * 2 + 0] = a10;
        o4[(size_t)n1 * 16 + gc * 2 + 1] = a11;
    }

    float vs[8], vq[8];
    {
        const float e0[8] = {a00.x, a00.y, a00.z, a00.w,
                             a01.x, a01.y, a01.z, a01.w};
        const float e1[8] = {a10.x, a10.y, a10.z, a10.w,
                             a11.x, a11.y, a11.z, a11.w};
        #pragma unroll
        for (int c = 0; c < 8; c++) {
            const float v0 = e0[c] * msk0;
            const float v1 = e1[c] * msk1;
            vs[c] = v0 + v1;
            vq[c] = v0 * e0[c] + v1 * e1[c];
        }
    }
    #pragma unroll
    for (int o = 8; o < 64; o <<= 1) {
        #pragma unroll
        for (int c = 0; c < 8; c++) {
            vs[c] += __shfl_xor(vs[c], o);
            vq[c] += __shfl_xor(vq[c], o);
        }
    }
    __syncthreads();    // all lW reads done before redS/redQ reuse the union
    float* redS = uni;                      // [8][64]
    float* redQ = uni + 512;
    const int lane = t & 63;
    const int w = t >> 6;
    if (lane < 8) {     // lane==gc for these lanes
        #pragma unroll
        for (int c = 0; c < 8; c++) {
            redS[w * 64 + lane * 8 + c] = vs[c];
            redQ[w * 64 + lane * 8 + c] = vq[c];
        }
    }
    __syncthreads();
    if (t < 64) {
        float s = 0.f, qq = 0.f;
        #pragma unroll
        for (int w2 = 0; w2 < 8; w2++) {
            s  += redS[w2 * 64 + t];
            qq += redQ[w2 * 64 + t];
        }
        const int sl = (b & (NSPREAD - 1)) * 64;    // spread slice
        unsafeAtomicAdd(&cs[sl + t], s);
        unsafeAtomicAdd(&css[sl + t], qq);
    }
}

// ---------------------------------------------------------------------------
// K_mlp2 (512 threads, 128-row tile — R10, kept: +3us win):
//  out = relu(BN(h1)) @ W2 + b2.  scl/sft sum the 16 spread slices.
// ---------------------------------------------------------------------------
__global__ __launch_bounds__(512) void k_mlp2(
    const float* h1, const float* __restrict__ W2, const float* __restrict__ b2,
    const float* __restrict__ gamma, const float* __restrict__ beta,
    const float* __restrict__ cs, const float* __restrict__ css,
    float* out)
{
    __shared__ float lin[MT][68];
    __shared__ float lW[4096];
    __shared__ float scl[64];
    __shared__ float sft[64];
    const int t = threadIdx.x;
    const int nbase = blockIdx.x * MT;

    if (t < 64) {
        float s = 0.f, qq = 0.f;
        #pragma unroll
        for (int i = 0; i < NSPREAD; i++) {
            s  += cs[i * 64 + t];
            qq += css[i * 64 + t];
        }
        const float inv = 1.0f / (float)N_NODESC;
        const float mu = s * inv;
        const float var = qq * inv - mu * mu;
        const float rs = rsqrtf(var + BN_EPSC);
        const float sc = rs * gamma[t];
        scl[t] = sc;
        sft[t] = fmaf(-mu, sc, beta[t]);
    }
    {
        const float4* W4 = (const float4*)W2;
        float4* lW4 = (float4*)lW;
        lW4[t] = W4[t];
        lW4[512 + t] = W4[512 + t];
    }
    __syncthreads();
    {
        const float4* h4 = (const float4*)h1;
        #pragma unroll
        for (int i = 0; i < 4; i++) {
            const int fidx = i * 512 + t;
            const int row = fidx >> 4;
            const int q = fidx & 15;
            const int n = nbase + row;
            float4 v = make_float4(0.f, 0.f, 0.f, 0.f);
            if (n < N_NODESC) {
                const float4 h = h4[(size_t)n * 16 + q];
                const int c = q * 4;
                v.x = fmaxf(fmaf(h.x, scl[c + 0], sft[c + 0]), 0.f);
                v.y = fmaxf(fmaf(h.y, scl[c + 1], sft[c + 1]), 0.f);
                v.z = fmaxf(fmaf(h.z, scl[c + 2], sft[c + 2]), 0.f);
                v.w = fmaxf(fmaf(h.w, scl[c + 3], sft[c + 3]), 0.f);
            }
            *(float4*)&lin[row][q * 4] = v;
        }
    }
    __syncthreads();

    const int g = t & 7;           // col group: cols [g*8, g*8+8)
    const int r0 = t >> 3;         // rows r0, r0+64
    const float4* lW4 = (const float4*)lW;
    const float4* b4 = (const float4*)b2;
    const float4 bb0 = b4[g * 2 + 0];
    const float4 bb1 = b4[g * 2 + 1];
    float4 a00 = bb0, a01 = bb1;
    float4 a10 = bb0, a11 = bb1;
    for (int k = 0; k < 64; k++) {
        const float v0 = lin[r0][k];
        const float v1 = lin[r0 + 64][k];
        const float4 w0 = lW4[k * 16 + g * 2 + 0];
        const float4 w1 = lW4[k * 16 + g * 2 + 1];
        a00.x = fmaf(v0, w0.x, a00.x); a00.y = fmaf(v0, w0.y, a00.y);
        a00.z = fmaf(v0, w0.z, a00.z); a00.w = fmaf(v0, w0.w, a00.w);
        a01.x = fmaf(v0, w1.x, a01.x); a01.y = fmaf(v0, w1.y, a01.y);
        a01.z = fmaf(v0, w1.z, a01.z); a01.w = fmaf(v0, w1.w, a01.w);
        a10.x = fmaf(v1, w0.x, a10.x); a10.y = fmaf(v1, w0.y, a10.y);
        a10.z = fmaf(v1, w0.z, a10.z); a10.w = fmaf(v1, w0.w, a10.w);
        a11.x = fmaf(v1, w1.x, a11.x); a11.y = fmaf(v1, w1.y, a11.y);
        a11.z = fmaf(v1, w1.z, a11.z); a11.w = fmaf(v1, w1.w, a11.w);
    }
    float4* o4 = (float4*)out;
    const int n0 = nbase + r0;
    const int n1 = n0 + 64;
    if (n0 < N_NODESC) {
        o4[(size_t)n0 * 16 + g * 2 + 0] = a00;
        o4[(size_t)n0 * 16 + g * 2 + 1] = a01;
    }
    if (n1 < N_NODESC) {
        o4[(size_t)n1 * 16 + g * 2 + 0] = a10;
        o4[(size_t)n1 * 16 + g * 2 + 1] = a11;
    }
}

// ---------------------------------------------------------------------------
extern "C" void kernel_launch(void* const* d_in, const int* in_sizes, int n_in,
                              void* d_out, int out_size, void* d_ws, size_t ws_size,
                              hipStream_t stream) {
    const float* x     = (const float*)d_in[0];
    const float* emb   = (const float*)d_in[1];
    const float* eps   = (const float*)d_in[2];
    const float* W1    = (const float*)d_in[3];
    const float* b1    = (const float*)d_in[4];
    const float* gamma = (const float*)d_in[5];
    const float* beta  = (const float*)d_in[6];
    const float* W2    = (const float*)d_in[7];
    const float* b2    = (const float*)d_in[8];
    const int*   ei    = (const int*)d_in[9];
    const int*   ea    = (const int*)d_in[10];
    float* out = (float*)d_out;

    // ws: [cs 16x64][css 16x64][gcur NBUCK][tmp NBUCK*BCAPG][xh N*64 bf16]
    float* ws    = (float*)d_ws;
    float* cs    = ws;                      // [NSPREAD][64]
    float* css   = ws + NSPREAD * 64;       // [NSPREAD][64]
    int*   gcur  = (int*)(ws + 2 * NSPREAD * 64);
    int*   tmp   = gcur + NBUCK;
    ushort* xh   = (ushort*)(tmp + (size_t)NBUCK * BCAPG);

    // zero cs/css slices + gcur (12.3 KB)
    hipMemsetAsync(d_ws, 0, (size_t)(2 * NSPREAD * 64 + NBUCK) * sizeof(int), stream);

    k_castsort<<<SBLK, 1024, 0, stream>>>(ei, ea, x, (uint2*)xh, gcur, tmp);
    k_aggmlp1<<<NUSED, 512, 0, stream>>>(xh, emb, x, eps, gcur, tmp,
                                         W1, b1, out, cs, css);   // h1 -> d_out
    k_mlp2<<<NUSED, 512, 0, stream>>>(out, W2, b2, gamma, beta, cs, css, out);
}

// Round 12
// 197.596 us; speedup vs baseline: 1.0014x; 1.0014x over previous
//
#include <hip/hip_runtime.h>

#define N_NODESC 100000
#define N_EDGESC 1600000
#define BN_EPSC 1e-5f
#define NBUCK 1024              // coarse buckets (dst>>7, 128 nodes each), 782 used
#define NUSED 782               // ceil(100000/128)
#define SBLK 512                // castsort blocks (R12: 256->512, 2 blocks/CU)
#define EPB (N_EDGESC / SBLK)   // 3125 edges per block
#define MT 128                  // nodes per MLP block
#define BCAPG 2304              // global per-bucket stride (mean 1562, ~18 sigma)
#define NSPREAD 16              // BN-stat atomic spreading (Guideline 12)

// ---------------------------------------------------------------------------
// K_castsort (R12: SBLK 512): bf16 cast + per-block bucket sort.
//  R11 budget arithmetic put this at ~42us vs a 9us traffic floor with
//  1 block/CU (grid 256) — phase latencies fully exposed.  512 blocks:
//  EPB 3125, ledge 12.6KB -> ~29KB LDS -> 2 blocks/CU, 32 waves/CU,
//  half the per-phase work, phases of the two blocks interleave.
// packed = src(17b) | attr<<17(2b) | (dst&127)<<19(7b).
// ---------------------------------------------------------------------------
__global__ __launch_bounds__(1024) void k_castsort(
    const int* __restrict__ ei, const int* __restrict__ ea,
    const float* __restrict__ x, uint2* __restrict__ xh4,
    int* __restrict__ gcur, int* __restrict__ tmp)
{
    __shared__ int ledge[EPB + 22];     // 3147 sorted packed edges
    __shared__ int cnt[NBUCK];
    __shared__ int cstart[NBUCK + 1];
    __shared__ int cur[NBUCK];
    __shared__ int gofs[NBUCK];
    __shared__ int wtot[16];
    const int t = threadIdx.x;
    const int k = blockIdx.x;

    cnt[t] = 0;
    {   // ---- bf16 cast, batched (4 x 1024-thread strides over 1.6M f4) --
        const float4* x4 = (const float4*)x;
        const int g = k * 1024 + t;
        float4 v[4];
        bool m[4];
        #pragma unroll
        for (int i = 0; i < 4; i++) {
            const int idx = g + i * (SBLK * 1024);
            m[i] = (idx < N_NODESC * 16);
            if (m[i]) v[i] = x4[idx];
        }
        #pragma unroll
        for (int i = 0; i < 4; i++) {
            if (m[i]) {
                const int idx = g + i * (SBLK * 1024);
                unsigned int a = __float_as_uint(v[i].x);
                unsigned int b = __float_as_uint(v[i].y);
                unsigned int c = __float_as_uint(v[i].z);
                unsigned int d = __float_as_uint(v[i].w);
                a = (a + 0x7FFFu + ((a >> 16) & 1u)) >> 16;
                b = (b + 0x7FFFu + ((b >> 16) & 1u)) >> 16;
                c = (c + 0x7FFFu + ((c >> 16) & 1u)) >> 16;
                d = (d + 0x7FFFu + ((d >> 16) & 1u)) >> 16;
                xh4[idx] = make_uint2(a | (b << 16), c | (d << 16));
            }
        }
    }
    __syncthreads();        // cnt zeroed before counting

    int pk[4], bk[4];
    const int base = k * EPB;
    #pragma unroll
    for (int i = 0; i < 4; i++) {
        const int e = base + i * 1024 + t;
        if (e < base + EPB) {
            const int src = ei[e];
            const int dst = ei[N_EDGESC + e];
            const int a = ea[e];
            pk[i] = src | (a << 17) | ((dst & 127) << 19);
            bk[i] = dst >> 7;
            atomicAdd(&cnt[bk[i]], 1);
        } else bk[i] = -1;
    }
    __syncthreads();

    {   // exclusive scan of 1024 counts
        const int lane = t & 63;
        const int w = t >> 6;
        const int v = cnt[t];
        int inc = v;
        #pragma unroll
        for (int d = 1; d < 64; d <<= 1) {
            const int u = __shfl_up(inc, d);
            if (lane >= d) inc += u;
        }
        if (lane == 63) wtot[w] = inc;
        __syncthreads();
        int add = 0;
        #pragma unroll
        for (int w2 = 0; w2 < 16; w2++) if (w2 < w) add += wtot[w2];
        const int ex = inc - v + add;
        cstart[t] = ex;
        cur[t] = ex;
        if (t == 1023) cstart[NBUCK] = ex + v;
    }
    __syncthreads();

    #pragma unroll
    for (int i = 0; i < 4; i++) {
        if (bk[i] >= 0) {
            const int pos = atomicAdd(&cur[bk[i]], 1);
            ledge[pos] = pk[i];
        }
    }
    {
        const int c = cnt[t];
        if (c > 0) gofs[t] = atomicAdd(&gcur[t], c);
    }
    __syncthreads();

    for (int i = t; i < EPB; i += 1024) {
        int lo = 0, hi = NBUCK;
        #pragma unroll
        for (int s = 0; s < 10; s++) {
            const int mid = (lo + hi) >> 1;
            if (cstart[mid] <= i) lo = mid; else hi = mid;
        }
        const int o = gofs[lo] + (i - cstart[lo]);
        if (o < BCAPG) tmp[lo * BCAPG + o] = ledge[i];
    }
}

// ---------------------------------------------------------------------------
// K_aggmlp1 — R9-measured 64.5us version, restored verbatim:
//  static phase A, early W1 staging into separate lW (hides under sort;
//  R11's late-staging union cost 3us), spread BN atomics, k+=2 GEMM.
//  R11 refuted the residency theory (3 blocks/CU at 54KB: no gain) —
//  this structure's floor is ~64.5us; leave it alone.
// ---------------------------------------------------------------------------
__global__ __launch_bounds__(512) void k_aggmlp1(
    const ushort* __restrict__ xh, const float* __restrict__ emb,
    const float* __restrict__ x, const float* __restrict__ epsp,
    const int* __restrict__ gcur, const int* __restrict__ tmp,
    const float* __restrict__ W1, const float* __restrict__ b1,
    float* __restrict__ out, float* __restrict__ cs, float* __restrict__ css)
{
    __shared__ int packedL[BCAPG];      // 9216B; aliased by redS/redQ at end
    __shared__ float lin[MT][68];       // 34816B
    __shared__ float lW[4096];          // 16384B
    __shared__ int cnt[128];
    __shared__ int cst[128];
    __shared__ int cur[128];
    __shared__ float emL[4][68];        // padded: rows 68 words apart
    const int t = threadIdx.x;
    const int b = blockIdx.x;
    const int start = b * BCAPG;

    {   // ---- stage W1 early: latency hides under the whole sort phase ---
        const float4* W4 = (const float4*)W1;
        float4* lW4s = (float4*)lW;
        lW4s[t] = W4[t];
        lW4s[512 + t] = W4[512 + t];
    }
    int cntb = gcur[b];
    if (cntb > BCAPG) cntb = BCAPG;
    if (t < 128) cnt[t] = 0;
    if (t < 256) emL[t >> 6][t & 63] = emb[t];
    __syncthreads();

    // pass 1: per-node counts
    for (int e = t; e < cntb; e += 512)
        atomicAdd(&cnt[(tmp[start + e] >> 19) & 127], 1);
    __syncthreads();
    if (t < 64) {   // scan 128 counts (two 64-lane halves)
        const int lane = t;
        const int v0 = cnt[lane];
        const int v1 = cnt[64 + lane];
        int i0 = v0, i1 = v1;
        #pragma unroll
        for (int d = 1; d < 64; d <<= 1) {
            const int u0 = __shfl_up(i0, d);
            const int u1 = __shfl_up(i1, d);
            if (lane >= d) { i0 += u0; i1 += u1; }
        }
        const int tot0 = __shfl(i0, 63);
        cst[lane] = i0 - v0;
        cst[64 + lane] = tot0 + i1 - v1;
        cur[lane] = i0 - v0;
        cur[64 + lane] = tot0 + i1 - v1;
    }
    __syncthreads();
    // pass 2: place node-sorted into LDS
    for (int e = t; e < cntb; e += 512) {
        const int p = tmp[start + e];
        const int pos = atomicAdd(&cur[(p >> 19) & 127], 1);
        if (pos < BCAPG) packedL[pos] = p;
    }
    __syncthreads();

    // ---- phase A: aggregate; group g -> nodes g*2,g*2+1; lane q = octet -
    {
        const int g = t >> 3;
        const int q = t & 7;                 // floats [q*8, q*8+8)
        const float sc1 = 1.0f + epsp[0];
        const uint4* xv8 = (const uint4*)xh; // 16B = 8 bf16 per lane
        const float4* x4 = (const float4*)x;
        const float* eq = &emL[0][0] + q * 8;
        for (int j = 0; j < 2; j++) {
            const int nl = g * 2 + j;
            const int n = b * 128 + nl;
            int e = cst[nl];
            const int ee = cur[nl];           // cur == end after pass 2
            float4 aL = make_float4(0.f, 0.f, 0.f, 0.f);
            float4 aH = make_float4(0.f, 0.f, 0.f, 0.f);
            if (n < N_NODESC) {
                const float4 v0 = x4[(size_t)n * 16 + q * 2];
                const float4 v1 = x4[(size_t)n * 16 + q * 2 + 1];
                aL.x = sc1 * v0.x; aL.y = sc1 * v0.y;
                aL.z = sc1 * v0.z; aL.w = sc1 * v0.w;
                aH.x = sc1 * v1.x; aH.y = sc1 * v1.y;
                aH.z = sc1 * v1.z; aH.w = sc1 * v1.w;
            }
            for (; e + 2 <= ee; e += 2) {
                const int p0 = packedL[e];
                const int p1 = packedL[e + 1];
                const uint4 u0 = xv8[(size_t)(p0 & 0x1FFFF) * 8 + q];
                const uint4 u1 = xv8[(size_t)(p1 & 0x1FFFF) * 8 + q];
                const float* e0 = eq + ((p0 >> 17) & 3) * 68;
                const float* e1 = eq + ((p1 >> 17) & 3) * 68;
                const float4 t0L = *(const float4*)(e0);
                const float4 t0H = *(const float4*)(e0 + 4);
                const float4 t1L = *(const float4*)(e1);
                const float4 t1H = *(const float4*)(e1 + 4);
                aL.x += fmaxf(__uint_as_float(u0.x << 16)          + t0L.x, 0.f)
                      + fmaxf(__uint_as_float(u1.x << 16)          + t1L.x, 0.f);
                aL.y += fmaxf(__uint_as_float(u0.x & 0xFFFF0000u)  + t0L.y, 0.f)
                      + fmaxf(__uint_as_float(u1.x & 0xFFFF0000u)  + t1L.y, 0.f);
                aL.z += fmaxf(__uint_as_float(u0.y << 16)          + t0L.z, 0.f)
                      + fmaxf(__uint_as_float(u1.y << 16)          + t1L.z, 0.f);
                aL.w += fmaxf(__uint_as_float(u0.y & 0xFFFF0000u)  + t0L.w, 0.f)
                      + fmaxf(__uint_as_float(u1.y & 0xFFFF0000u)  + t1L.w, 0.f);
                aH.x += fmaxf(__uint_as_float(u0.z << 16)          + t0H.x, 0.f)
                      + fmaxf(__uint_as_float(u1.z << 16)          + t1H.x, 0.f);
                aH.y += fmaxf(__uint_as_float(u0.z & 0xFFFF0000u)  + t0H.y, 0.f)
                      + fmaxf(__uint_as_float(u1.z & 0xFFFF0000u)  + t1H.y, 0.f);
                aH.z += fmaxf(__uint_as_float(u0.w << 16)          + t0H.z, 0.f)
                      + fmaxf(__uint_as_float(u1.w << 16)          + t1H.z, 0.f);
                aH.w += fmaxf(__uint_as_float(u0.w & 0xFFFF0000u)  + t0H.w, 0.f)
                      + fmaxf(__uint_as_float(u1.w & 0xFFFF0000u)  + t1H.w, 0.f);
            }
            for (; e < ee; e++) {
                const int p0 = packedL[e];
                const uint4 u0 = xv8[(size_t)(p0 & 0x1FFFF) * 8 + q];
                const float* e0 = eq + ((p0 >> 17) & 3) * 68;
                const float4 t0L = *(const float4*)(e0);
                const float4 t0H = *(const float4*)(e0 + 4);
                aL.x += fmaxf(__uint_as_float(u0.x << 16)         + t0L.x, 0.f);
                aL.y += fmaxf(__uint_as_float(u0.x & 0xFFFF0000u) + t0L.y, 0.f);
                aL.z += fmaxf(__uint_as_float(u0.y << 16)         + t0L.z, 0.f);
                aL.w += fmaxf(__uint_as_float(u0.y & 0xFFFF0000u) + t0L.w, 0.f);
                aH.x += fmaxf(__uint_as_float(u0.z << 16)         + t0H.x, 0.f);
                aH.y += fmaxf(__uint_as_float(u0.z & 0xFFFF0000u) + t0H.y, 0.f);
                aH.z += fmaxf(__uint_as_float(u0.w << 16)         + t0H.z, 0.f);
                aH.w += fmaxf(__uint_as_float(u0.w & 0xFFFF0000u) + t0H.w, 0.f);
            }
            // h_pre -> LDS tile (own cells only; no cross-thread hazard)
            *(float4*)&lin[nl][q * 8]     = aL;
            *(float4*)&lin[nl][q * 8 + 4] = aH;
        }
    }
    __syncthreads();    // lin complete + lW visible

    // ---- phase B: h1 = lin @ W1 + b1 ; store; BN sums -------------------
    const int gc = t & 7;          // col group: cols [gc*8, gc*8+8)
    const int r0 = t >> 3;         // rows r0, r0+64
    const float4* lW4 = (const float4*)lW;
    const float4* b4 = (const float4*)b1;
    const float4 bb0 = b4[gc * 2 + 0];
    const float4 bb1 = b4[gc * 2 + 1];
    float4 a00 = bb0, a01 = bb1;   // row r0
    float4 a10 = bb0, a11 = bb1;   // row r0+64
    for (int k = 0; k < 64; k += 2) {
        const float v0a = lin[r0][k];
        const float v0b = lin[r0][k + 1];
        const float v1a = lin[r0 + 64][k];
        const float v1b = lin[r0 + 64][k + 1];
        const float4 w0a = lW4[k * 16 + gc * 2 + 0];
        const float4 w1a = lW4[k * 16 + gc * 2 + 1];
        const float4 w0b = lW4[(k + 1) * 16 + gc * 2 + 0];
        const float4 w1b = lW4[(k + 1) * 16 + gc * 2 + 1];
        a00.x = fmaf(v0a, w0a.x, a00.x); a00.y = fmaf(v0a, w0a.y, a00.y);
        a00.z = fmaf(v0a, w0a.z, a00.z); a00.w = fmaf(v0a, w0a.w, a00.w);
        a01.x = fmaf(v0a, w1a.x, a01.x); a01.y = fmaf(v0a, w1a.y, a01.y);
        a01.z = fmaf(v0a, w1a.z, a01.z); a01.w = fmaf(v0a, w1a.w, a01.w);
        a10.x = fmaf(v1a, w0a.x, a10.x); a10.y = fmaf(v1a, w0a.y, a10.y);
        a10.z = fmaf(v1a, w0a.z, a10.z); a10.w = fmaf(v1a, w0a.w, a10.w);
        a11.x = fmaf(v1a, w1a.x, a11.x); a11.y = fmaf(v1a, w1a.y, a11.y);
        a11.z = fmaf(v1a, w1a.z, a11.z); a11.w = fmaf(v1a, w1a.w, a11.w);
        a00.x = fmaf(v0b, w0b.x, a00.x); a00.y = fmaf(v0b, w0b.y, a00.y);
        a00.z = fmaf(v0b, w0b.z, a00.z); a00.w = fmaf(v0b, w0b.w, a00.w);
        a01.x = fmaf(v0b, w1b.x, a01.x); a01.y = fmaf(v0b, w1b.y, a01.y);
        a01.z = fmaf(v0b, w1b.z, a01.z); a01.w = fmaf(v0b, w1b.w, a01.w);
        a10.x = fmaf(v1b, w0b.x, a10.x); a10.y = fmaf(v1b, w0b.y, a10.y);
        a10.z = fmaf(v1b, w0b.z, a10.z); a10.w = fmaf(v1b, w0b.w, a10.w);
        a11.x = fmaf(v1b, w1b.x, a11.x); a11.y = fmaf(v1b, w1b.y, a11.y);
        a11.z = fmaf(v1b, w1b.z, a11.z); a11.w = fmaf(v1b, w1b.w, a11.w);
    }
    const int n0 = b * MT + r0;
    const int n1 = n0 + 64;
    const float msk0 = (n0 < N_NODESC) ? 1.0f : 0.0f;
    const float msk1 = (n1 < N_NODESC) ? 1.0f : 0.0f;
    float4* o4 = (float4*)out;
    if (n0 < N_NODESC) {
        o4[(size_t)n0 * 16 + gc * 2 + 0] = a00;
        o4[(size_t)n0 * 16 + gc * 2 + 1] = a01;
    }
    if (n1 < N_NODESC) {
        o4[(size_t)n1 * 16 + gc * 2 + 0] = a10;
        o4[(size_t)n1 * 16 + gc * 2 + 1] = a11;
    }

    float vs[8], vq[8];
    {
        const float e0[8] = {a00.x, a00.y, a00.z, a00.w,
                             a01.x, a01.y, a01.z, a01.w};
        const float e1[8] = {a10.x, a10.y, a10.z, a10.w,
                             a11.x, a11.y, a11.z, a11.w};
        #pragma unroll
        for (int c = 0; c < 8; c++) {
            const float v0 = e0[c] * msk0;
            const float v1 = e1[c] * msk1;
            vs[c] = v0 + v1;
            vq[c] = v0 * e0[c] + v1 * e1[c];
        }
    }
    #pragma unroll
    for (int o = 8; o < 64; o <<= 1) {
        #pragma unroll
        for (int c = 0; c < 8; c++) {
            vs[c] += __shfl_xor(vs[c], o);
            vq[c] += __shfl_xor(vq[c], o);
        }
    }
    __syncthreads();    // all lin reads done before redS/redQ alias packedL
    float* redS = (float*)packedL;          // [8][64]
    float* redQ = redS + 512;
    const int lane = t & 63;
    const int w = t >> 6;
    if (lane < 8) {     // lane==gc for these lanes
        #pragma unroll
        for (int c = 0; c < 8; c++) {
            redS[w * 64 + lane * 8 + c] = vs[c];
            redQ[w * 64 + lane * 8 + c] = vq[c];
        }
    }
    __syncthreads();
    if (t < 64) {
        float s = 0.f, qq = 0.f;
        #pragma unroll
        for (int w2 = 0; w2 < 8; w2++) {
            s  += redS[w2 * 64 + t];
            qq += redQ[w2 * 64 + t];
        }
        const int sl = (b & (NSPREAD - 1)) * 64;    // spread slice
        unsafeAtomicAdd(&cs[sl + t], s);
        unsafeAtomicAdd(&css[sl + t], qq);
    }
}

// ---------------------------------------------------------------------------
// K_mlp2 (512 threads, 128-row tile — R10, kept: +3us win):
//  out = relu(BN(h1)) @ W2 + b2.  scl/sft sum the 16 spread slices.
// ---------------------------------------------------------------------------
__global__ __launch_bounds__(512) void k_mlp2(
    const float* h1, const float* __restrict__ W2, const float* __restrict__ b2,
    const float* __restrict__ gamma, const float* __restrict__ beta,
    const float* __restrict__ cs, const float* __restrict__ css,
    float* out)
{
    __shared__ float lin[MT][68];
    __shared__ float lW[4096];
    __shared__ float scl[64];
    __shared__ float sft[64];
    const int t = threadIdx.x;
    const int nbase = blockIdx.x * MT;

    if (t < 64) {
        float s = 0.f, qq = 0.f;
        #pragma unroll
        for (int i = 0; i < NSPREAD; i++) {
            s  += cs[i * 64 + t];
            qq += css[i * 64 + t];
        }
        const float inv = 1.0f / (float)N_NODESC;
        const float mu = s * inv;
        const float var = qq * inv - mu * mu;
        const float rs = rsqrtf(var + BN_EPSC);
        const float sc = rs * gamma[t];
        scl[t] = sc;
        sft[t] = fmaf(-mu, sc, beta[t]);
    }
    {
        const float4* W4 = (const float4*)W2;
        float4* lW4 = (float4*)lW;
        lW4[t] = W4[t];
        lW4[512 + t] = W4[512 + t];
    }
    __syncthreads();
    {
        const float4* h4 = (const float4*)h1;
        #pragma unroll
        for (int i = 0; i < 4; i++) {
            const int fidx = i * 512 + t;
            const int row = fidx >> 4;
            const int q = fidx & 15;
            const int n = nbase + row;
            float4 v = make_float4(0.f, 0.f, 0.f, 0.f);
            if (n < N_NODESC) {
                const float4 h = h4[(size_t)n * 16 + q];
                const int c = q * 4;
                v.x = fmaxf(fmaf(h.x, scl[c + 0], sft[c + 0]), 0.f);
                v.y = fmaxf(fmaf(h.y, scl[c + 1], sft[c + 1]), 0.f);
                v.z = fmaxf(fmaf(h.z, scl[c + 2], sft[c + 2]), 0.f);
                v.w = fmaxf(fmaf(h.w, scl[c + 3], sft[c + 3]), 0.f);
            }
            *(float4*)&lin[row][q * 4] = v;
        }
    }
    __syncthreads();

    const int g = t & 7;           // col group: cols [g*8, g*8+8)
    const int r0 = t >> 3;         // rows r0, r0+64
    const float4* lW4 = (const float4*)lW;
    const float4* b4 = (const float4*)b2;
    const float4 bb0 = b4[g * 2 + 0];
    const float4 bb1 = b4[g * 2 + 1];
    float4 a00 = bb0, a01 = bb1;
    float4 a10 = bb0, a11 = bb1;
    for (int k = 0; k < 64; k++) {
        const float v0 = lin[r0][k];
        const float v1 = lin[r0 + 64][k];
        const float4 w0 = lW4[k * 16 + g * 2 + 0];
        const float4 w1 = lW4[k * 16 + g * 2 + 1];
        a00.x = fmaf(v0, w0.x, a00.x); a00.y = fmaf(v0, w0.y, a00.y);
        a00.z = fmaf(v0, w0.z, a00.z); a00.w = fmaf(v0, w0.w, a00.w);
        a01.x = fmaf(v0, w1.x, a01.x); a01.y = fmaf(v0, w1.y, a01.y);
        a01.z = fmaf(v0, w1.z, a01.z); a01.w = fmaf(v0, w1.w, a01.w);
        a10.x = fmaf(v1, w0.x, a10.x); a10.y = fmaf(v1, w0.y, a10.y);
        a10.z = fmaf(v1, w0.z, a10.z); a10.w = fmaf(v1, w0.w, a10.w);
        a11.x = fmaf(v1, w1.x, a11.x); a11.y = fmaf(v1, w1.y, a11.y);
        a11.z = fmaf(v1, w1.z, a11.z); a11.w = fmaf(v1, w1.w, a11.w);
    }
    float4* o4 = (float4*)out;
    const int n0 = nbase + r0;
    const int n1 = n0 + 64;
    if (n0 < N_NODESC) {
        o4[(size_t)n0 * 16 + g * 2 + 0] = a00;
        o4[(size_t)n0 * 16 + g * 2 + 1] = a01;
    }
    if (n1 < N_NODESC) {
        o4[(size_t)n1 * 16 + g * 2 + 0] = a10;
        o4[(size_t)n1 * 16 + g * 2 + 1] = a11;
    }
}

// ---------------------------------------------------------------------------
extern "C" void kernel_launch(void* const* d_in, const int* in_sizes, int n_in,
                              void* d_out, int out_size, void* d_ws, size_t ws_size,
                              hipStream_t stream) {
    const float* x     = (const float*)d_in[0];
    const float* emb   = (const float*)d_in[1];
    const float* eps   = (const float*)d_in[2];
    const float* W1    = (const float*)d_in[3];
    const float* b1    = (const float*)d_in[4];
    const float* gamma = (const float*)d_in[5];
    const float* beta  = (const float*)d_in[6];
    const float* W2    = (const float*)d_in[7];
    const float* b2    = (const float*)d_in[8];
    const int*   ei    = (const int*)d_in[9];
    const int*   ea    = (const int*)d_in[10];
    float* out = (float*)d_out;

    // ws: [cs 16x64][css 16x64][gcur NBUCK][tmp NBUCK*BCAPG][xh N*64 bf16]
    float* ws    = (float*)d_ws;
    float* cs    = ws;                      // [NSPREAD][64]
    float* css   = ws + NSPREAD * 64;       // [NSPREAD][64]
    int*   gcur  = (int*)(ws + 2 * NSPREAD * 64);
    int*   tmp   = gcur + NBUCK;
    ushort* xh   = (ushort*)(tmp + (size_t)NBUCK * BCAPG);

    // zero cs/css slices + gcur (12.3 KB)
    hipMemsetAsync(d_ws, 0, (size_t)(2 * NSPREAD * 64 + NBUCK) * sizeof(int), stream);

    k_castsort<<<SBLK, 1024, 0, stream>>>(ei, ea, x, (uint2*)xh, gcur, tmp);
    k_aggmlp1<<<NUSED, 512, 0, stream>>>(xh, emb, x, eps, gcur, tmp,
                                         W1, b1, out, cs, css);   // h1 -> d_out
    k_mlp2<<<NUSED, 512, 0, stream>>>(out, W2, b2, gamma, beta, cs, css, out);
}